// Round 16
// baseline (297.375 us; speedup 1.0000x reference)
//
#include <hip/hip_runtime.h>

typedef __bf16 bf16;
typedef __bf16 bf16x2 __attribute__((ext_vector_type(2)));
typedef __bf16 bf16x4 __attribute__((ext_vector_type(4)));
typedef __bf16 bf16x8 __attribute__((ext_vector_type(8)));
typedef float f32x4 __attribute__((ext_vector_type(4)));

typedef __attribute__((address_space(1))) const unsigned int gq_t;
typedef __attribute__((address_space(3))) unsigned int lq_t;

// ---------------------------------------------------------------------------
// fp32 -> bf16 converter, 8 elems/thread.
// ---------------------------------------------------------------------------
__global__ __launch_bounds__(256) void cvt_bf16(const float* __restrict__ in,
                                                bf16* __restrict__ out,
                                                int n8) {
  int i = blockIdx.x * 256 + threadIdx.x;
  if (i >= n8) return;
  f32x4 a = ((const f32x4*)in)[2 * i];
  f32x4 b = ((const f32x4*)in)[2 * i + 1];
  bf16x8 o;
#pragma unroll
  for (int j = 0; j < 4; ++j) {
    o[j] = (bf16)a[j];
    o[4 + j] = (bf16)b[j];
  }
  ((bf16x8*)out)[i] = o;
}

// ---------------------------------------------------------------------------
// GEMM for N%192==0 (G1): 256x192, BK=64, 512 thr — r15 proven. Unchanged.
// ---------------------------------------------------------------------------
template <typename TC, bool ADD_BIAS>
__global__ __launch_bounds__(512) void gemm_192(const bf16* __restrict__ A,
                                                const bf16* __restrict__ B,
                                                const float* __restrict__ bias,
                                                TC* __restrict__ C,
                                                int M, int N, int K, int lda) {
  __shared__ __align__(16) bf16 As[2][256 * 64];  // 64 KB
  __shared__ __align__(16) bf16 Bs[2][192 * 64];  // 48 KB
  const int tid = threadIdx.x;
  const int lane = tid & 63;
  const int wid = tid >> 6;
  const int wm = wid >> 2;
  const int wn = wid & 3;
  const int l16 = lane & 15;
  const int lhi = lane >> 4;
  const int lr = lane >> 3;

  const int nwg = gridDim.x * gridDim.y;
  const int bid0 = blockIdx.y * gridDim.x + blockIdx.x;
  const int swzb = (bid0 & 7) * (nwg >> 3) + (bid0 >> 3);
  const int m0 = (swzb / gridDim.x) * 256;
  const int n0 = (swzb % gridDim.x) * 192;

  const int nkt = K >> 6;

  f32x4 acc[8][3] = {};

  auto stageA = [&](int kt, int buf, int u) {
    const int chunk = wid * 4 + u;
    const int row = chunk * 8 + lr;
    const int cs = (lane & 7) ^ lr;
    const bf16* g = A + (size_t)(m0 + row) * lda + kt * 64 + cs * 8;
    __builtin_amdgcn_global_load_lds((gq_t*)g, (lq_t*)&As[buf][chunk * 512],
                                     16, 0, 0);
  };
  auto stageB = [&](int kt, int buf, int u) {
    const int chunk = wid * 3 + u;
    const int row = chunk * 8 + lr;
    const int cs = (lane & 7) ^ lr;
    const bf16* g = B + (size_t)(n0 + row) * K + kt * 64 + cs * 8;
    __builtin_amdgcn_global_load_lds((gq_t*)g, (lq_t*)&Bs[buf][chunk * 512],
                                     16, 0, 0);
  };

  stageA(0, 0, 0); stageA(0, 0, 1); stageA(0, 0, 2); stageA(0, 0, 3);
  stageB(0, 0, 0); stageB(0, 0, 1); stageB(0, 0, 2);
  asm volatile("s_waitcnt vmcnt(0)" ::: "memory");
  __builtin_amdgcn_sched_barrier(0);
  __builtin_amdgcn_s_barrier();

  for (int g = 0; g < nkt; ++g) {
    const int buf = g & 1;
    const bool donext = (g + 1) < nkt;
    const bf16* Asb = &As[buf][0];
    const bf16* Bsb = &Bs[buf][0];

    bf16x8 bfn[3][2];

#pragma unroll
    for (int q = 0; q < 4; ++q) {
      if (q == 0) {
#pragma unroll
        for (int nf = 0; nf < 3; ++nf) {
          const int nrow = wn * 48 + nf * 16 + l16;
          const int sw = nrow & 7;
#pragma unroll
          for (int ks = 0; ks < 2; ++ks) {
            const int slot = ks * 4 + lhi;
            bfn[nf][ks] =
                *(const bf16x8*)(Bsb + nrow * 64 + ((slot ^ sw) << 3));
          }
        }
      }
      bf16x8 af[2][2];
#pragma unroll
      for (int mf = 0; mf < 2; ++mf) {
        const int mrow = wm * 128 + (q * 2 + mf) * 16 + l16;
        const int sw = mrow & 7;
#pragma unroll
        for (int ks = 0; ks < 2; ++ks) {
          const int slot = ks * 4 + lhi;
          af[mf][ks] = *(const bf16x8*)(Asb + mrow * 64 + ((slot ^ sw) << 3));
        }
      }
      if (donext) {
        if (q == 0) {
          stageA(g + 1, buf ^ 1, 0);
          stageA(g + 1, buf ^ 1, 1);
          stageA(g + 1, buf ^ 1, 2);
          stageA(g + 1, buf ^ 1, 3);
        } else if (q == 1) {
          stageB(g + 1, buf ^ 1, 0);
          stageB(g + 1, buf ^ 1, 1);
          stageB(g + 1, buf ^ 1, 2);
        }
      }
      __builtin_amdgcn_s_barrier();
      asm volatile("s_waitcnt lgkmcnt(0)" ::: "memory");
      __builtin_amdgcn_sched_barrier(0);
      __builtin_amdgcn_s_setprio(1);
#pragma unroll
      for (int mf = 0; mf < 2; ++mf)
#pragma unroll
        for (int nf = 0; nf < 3; ++nf)
#pragma unroll
          for (int ks = 0; ks < 2; ++ks)
            acc[q * 2 + mf][nf] = __builtin_amdgcn_mfma_f32_16x16x32_bf16(
                af[mf][ks], bfn[nf][ks], acc[q * 2 + mf][nf], 0, 0, 0);
      __builtin_amdgcn_s_setprio(0);
      __builtin_amdgcn_s_barrier();
    }

    if (donext) {
      asm volatile("s_waitcnt vmcnt(0)" ::: "memory");
      __builtin_amdgcn_sched_barrier(0);
      __builtin_amdgcn_s_barrier();
    }
  }

#pragma unroll
  for (int i = 0; i < 8; ++i) {
    int row_base = m0 + wm * 128 + i * 16 + lhi * 4;
#pragma unroll
    for (int j = 0; j < 3; ++j) {
      int col = n0 + wn * 48 + j * 16 + l16;
      float bv = ADD_BIAS ? bias[col] : 0.0f;
#pragma unroll
      for (int r = 0; r < 4; ++r) {
        float val = acc[i][j][r] + bv;
        if constexpr (__is_same(TC, float))
          C[(size_t)(row_base + r) * N + col] = val;
        else
          C[(size_t)(row_base + r) * N + col] = (bf16)val;
      }
    }
  }
}

// ---------------------------------------------------------------------------
// Pipelined bf16 GEMM 256x128 (r13 proven) — G2 (N=1024). Unchanged.
// ---------------------------------------------------------------------------
template <typename TC, bool ADD_BIAS>
__global__ __launch_bounds__(512) void gemm_8ph(const bf16* __restrict__ A,
                                                const bf16* __restrict__ B,
                                                const float* __restrict__ bias,
                                                TC* __restrict__ C,
                                                int M, int N, int K, int lda) {
  __shared__ __align__(16) bf16 As[3][256 * 64];
  __shared__ __align__(16) bf16 Bs[3][128 * 64];
  const int tid = threadIdx.x;
  const int lane = tid & 63;
  const int wid = tid >> 6;
  const int wm = wid >> 2;
  const int wn = wid & 3;
  const int l16 = lane & 15;
  const int lhi = lane >> 4;
  const int lr = lane >> 3;

  const int nwg = gridDim.x * gridDim.y;
  const int bid0 = blockIdx.y * gridDim.x + blockIdx.x;
  const int swzb = (bid0 & 7) * (nwg >> 3) + (bid0 >> 3);
  const int m0 = (swzb / gridDim.x) * 256;
  const int n0 = (swzb % gridDim.x) * 128;

  const int nkt = K >> 6;

  f32x4 acc[8][2] = {};

  auto stageA = [&](int kt, int buf, int u) {
    const int chunk = wid * 4 + u;
    const int row = chunk * 8 + lr;
    const int cs = (lane & 7) ^ lr;
    const bf16* g = A + (size_t)(m0 + row) * lda + kt * 64 + cs * 8;
    __builtin_amdgcn_global_load_lds((gq_t*)g, (lq_t*)&As[buf][chunk * 512],
                                     16, 0, 0);
  };
  auto stageB = [&](int kt, int buf, int u) {
    const int chunk = wid * 2 + u;
    const int row = chunk * 8 + lr;
    const int cs = (lane & 7) ^ lr;
    const bf16* g = B + (size_t)(n0 + row) * K + kt * 64 + cs * 8;
    __builtin_amdgcn_global_load_lds((gq_t*)g, (lq_t*)&Bs[buf][chunk * 512],
                                     16, 0, 0);
  };

  stageA(0, 0, 0); stageA(0, 0, 1); stageA(0, 0, 2); stageA(0, 0, 3);
  stageB(0, 0, 0); stageB(0, 0, 1);
  stageA(1, 1, 0); stageA(1, 1, 1); stageA(1, 1, 2); stageA(1, 1, 3);
  stageB(1, 1, 0); stageB(1, 1, 1);
  asm volatile("s_waitcnt vmcnt(6)" ::: "memory");
  __builtin_amdgcn_sched_barrier(0);
  __builtin_amdgcn_s_barrier();

  for (int g = 0; g < nkt; ++g) {
    const int buf = g % 3;
    const int nbuf = (g + 2) % 3;
    const bool donext = (g + 2) < nkt;
    const bf16* Asb = &As[buf][0];
    const bf16* Bsb = &Bs[buf][0];

#pragma unroll
    for (int q = 0; q < 2; ++q) {
      bf16x8 af[4][2], bfn[2][2];
#pragma unroll
      for (int mf = 0; mf < 4; ++mf) {
        const int mrow = wm * 128 + (q * 4 + mf) * 16 + l16;
        const int sw = mrow & 7;
#pragma unroll
        for (int ks = 0; ks < 2; ++ks) {
          const int slot = ks * 4 + lhi;
          af[mf][ks] = *(const bf16x8*)(Asb + mrow * 64 + ((slot ^ sw) << 3));
        }
      }
#pragma unroll
      for (int nh = 0; nh < 2; ++nh) {
        const int nrow = wn * 32 + nh * 16 + l16;
        const int sw = nrow & 7;
#pragma unroll
        for (int ks = 0; ks < 2; ++ks) {
          const int slot = ks * 4 + lhi;
          bfn[nh][ks] = *(const bf16x8*)(Bsb + nrow * 64 + ((slot ^ sw) << 3));
        }
      }
      if (donext) {
        if (q == 0) {
          stageA(g + 2, nbuf, 0);
          stageA(g + 2, nbuf, 1);
          stageA(g + 2, nbuf, 2);
        } else {
          stageA(g + 2, nbuf, 3);
          stageB(g + 2, nbuf, 0);
          stageB(g + 2, nbuf, 1);
        }
      }
      __builtin_amdgcn_s_barrier();
      asm volatile("s_waitcnt lgkmcnt(0)" ::: "memory");
      __builtin_amdgcn_sched_barrier(0);
      __builtin_amdgcn_s_setprio(1);
#pragma unroll
      for (int mf = 0; mf < 4; ++mf)
#pragma unroll
        for (int nh = 0; nh < 2; ++nh)
#pragma unroll
          for (int ks = 0; ks < 2; ++ks)
            acc[q * 4 + mf][nh] = __builtin_amdgcn_mfma_f32_16x16x32_bf16(
                af[mf][ks], bfn[nh][ks], acc[q * 4 + mf][nh], 0, 0, 0);
      __builtin_amdgcn_s_setprio(0);
      __builtin_amdgcn_s_barrier();
    }

    if (g + 1 < nkt) {
      if (donext) {
        asm volatile("s_waitcnt vmcnt(6)" ::: "memory");
      } else {
        asm volatile("s_waitcnt vmcnt(0)" ::: "memory");
      }
      __builtin_amdgcn_sched_barrier(0);
      __builtin_amdgcn_s_barrier();
    }
  }

#pragma unroll
  for (int i = 0; i < 8; ++i) {
    int row_base = m0 + wm * 128 + i * 16 + lhi * 4;
#pragma unroll
    for (int j = 0; j < 2; ++j) {
      int col = n0 + wn * 32 + j * 16 + l16;
      float bv = ADD_BIAS ? bias[col] : 0.0f;
#pragma unroll
      for (int r = 0; r < 4; ++r) {
        float val = acc[i][j][r] + bv;
        if constexpr (__is_same(TC, float))
          C[(size_t)(row_base + r) * N + col] = val;
        else
          C[(size_t)(row_base + r) * N + col] = (bf16)val;
      }
    }
  }
}

// ---------------------------------------------------------------------------
// GEMM (legacy reg-staged, fp32 B): low-workspace fallback only.
// ---------------------------------------------------------------------------
template <typename TA, typename TC, bool ADD_BIAS>
__global__ __launch_bounds__(256) void gemm_bt(const TA* __restrict__ A,
                                               const float* __restrict__ B,
                                               const float* __restrict__ bias,
                                               TC* __restrict__ C,
                                               int M, int N, int K,
                                               int lda, int row0) {
  __shared__ __align__(16) bf16 As[128][72];
  __shared__ __align__(16) bf16 Bs[128][72];
  const int tid = threadIdx.x;
  const int lane = tid & 63;
  const int wid = tid >> 6;
  const int wr = wid >> 1, wc = wid & 1;
  const int m0 = blockIdx.y * 128;
  const int n0 = blockIdx.x * 128;
  const int l16 = lane & 15;
  const int lhi = lane >> 4;

  f32x4 acc[4][4] = {};

  for (int k0 = 0; k0 < K; k0 += 64) {
    __syncthreads();
#pragma unroll
    for (int p = 0; p < 8; ++p) {
      int v = tid + p * 256;
      int row = v >> 4;
      int kc = (v & 15) * 4;
      size_t ai = (size_t)(row0 + m0 + row) * lda + k0 + kc;
      size_t bi = (size_t)(n0 + row) * K + k0 + kc;
      bf16x4 ab, bb;
      if constexpr (__is_same(TA, float)) {
        f32x4 a4 = *(const f32x4*)((const float*)A + ai);
#pragma unroll
        for (int j = 0; j < 4; ++j) ab[j] = (bf16)a4[j];
      } else {
        ab = *(const bf16x4*)((const bf16*)A + ai);
      }
      f32x4 b4 = *(const f32x4*)(B + bi);
#pragma unroll
      for (int j = 0; j < 4; ++j) bb[j] = (bf16)b4[j];
      *(bf16x4*)(&As[row][kc]) = ab;
      *(bf16x4*)(&Bs[row][kc]) = bb;
    }
    __syncthreads();
#pragma unroll
    for (int ks = 0; ks < 2; ++ks) {
      bf16x8 af[4], bfr[4];
#pragma unroll
      for (int i = 0; i < 4; ++i) {
        af[i] = *(const bf16x8*)(&As[wr * 64 + i * 16 + l16][ks * 32 + lhi * 8]);
        bfr[i] = *(const bf16x8*)(&Bs[wc * 64 + i * 16 + l16][ks * 32 + lhi * 8]);
      }
#pragma unroll
      for (int i = 0; i < 4; ++i)
#pragma unroll
        for (int j = 0; j < 4; ++j)
          acc[i][j] = __builtin_amdgcn_mfma_f32_16x16x32_bf16(af[i], bfr[j],
                                                              acc[i][j], 0, 0, 0);
    }
  }

#pragma unroll
  for (int i = 0; i < 4; ++i) {
    int row_base = m0 + wr * 64 + i * 16 + lhi * 4;
#pragma unroll
    for (int j = 0; j < 4; ++j) {
      int col = n0 + wc * 64 + j * 16 + l16;
      float bv = ADD_BIAS ? bias[col] : 0.0f;
#pragma unroll
      for (int r = 0; r < 4; ++r) {
        float val = acc[i][j][r] + bv;
        if constexpr (__is_same(TC, float))
          C[(size_t)(row_base + r) * N + col] = val;
        else
          C[(size_t)(row_base + r) * N + col] = (bf16)val;
      }
    }
  }
}

// ---------------------------------------------------------------------------
// MFMA flash attention v11: occupancy push.
//  - r15 diagnosis: grid 512 = 2 blocks/CU was the residency binder (LDS 55KB
//    also capped at 2). r13->r14 evidence (12->16 waves/CU = 143->119 us) says
//    occupancy is the live lever; softmax VALU floor ~50 us needs cross-wave
//    overlap.
//  - Changes: (a) SINGLE-buffer Kt and Vt with 2 barriers/tile. Safe: all Kt
//    reads (QK^T) precede barrier-A -> K(t+1) writes after A; all Vt reads
//    (PV) precede barrier-B -> V(t+1) writes after B; every write->read pair
//    is separated by a __syncthreads (lgkm drained). Barrier count 1->2/tile
//    is measured-neutral (r4). (b) block = 8 waves x 16 q-rows = 128 rows ->
//    grid 1024 = 4 blocks/CU available; LDS 36.9 KB fits 4.
//  - Staging scheme byte-identical (waves 0-3 stage K, 4-7 stage V).
//  - Per-wave structure = r5-proven single 16-row sub-tile.
// ---------------------------------------------------------------------------
__global__ __launch_bounds__(512) void attn_fwd(bf16* __restrict__ qkv) {
  constexpr int S = 2048, D3 = 3072;
  constexpr float SCL = 0.18033688011112042f;  // 0.125 * log2(e)
  constexpr float THR = 11.5f;                 // 8 * log2(e)
  __shared__ __align__(16) bf16 Kt[64][72];     // [key][dim]   9.2 KB
  __shared__ __align__(16) bf16 Vt[64][72];     // [dim][key]   9.2 KB
  __shared__ __align__(16) bf16 Pq[8][16][72];  // per-wave    18.4 KB

  const int tid = threadIdx.x;
  const int lane = tid & 63;
  const int wid = tid >> 6;  // 0..7
  const int l16 = lane & 15, lhi = lane >> 4;

  // XCD-aware bijective swizzle (nwg % 8 == 0 in all launch paths).
  const int nwg = gridDim.x * gridDim.y;  // 1024 (full) / 256 (fallback)
  const int bid = blockIdx.y * gridDim.x + blockIdx.x;
  const int swz = (bid & 7) * (nwg >> 3) + (bid >> 3);
  const int bh = swz >> 4;                // 16 q-tiles (128 rows) per bh
  const int b = bh >> 4, h = bh & 15;
  const int q0 = (swz & 15) * 128 + wid * 16;  // wave owns rows q0..q0+15

  bf16* base = qkv + (size_t)b * S * D3;
  bf16* qbase = base + h * 64;
  const bf16* kbase = base + 1024 + h * 64;
  const bf16* vbase = base + 2048 + h * 64;

  // Q fragments (cached before in-place overwrite)
  bf16x8 qf[2];
#pragma unroll
  for (int ks = 0; ks < 2; ++ks)
    qf[ks] = *(const bf16x8*)(qbase + (size_t)(q0 + l16) * D3 + ks * 32 + lhi * 8);

  float m_i = -1e30f;   // running max, log2 domain
  float l_p = 0.0f;     // per-lane partial sum
  f32x4 o[4] = {};

  // staging split: waves 0-3 stage K, waves 4-7 stage V (wave-uniform)
  const int sg = tid >> 8;        // 0: K, 1: V
  const int kp = tid & 31;        // key pair 2kp, 2kp+1
  const int oc = (tid >> 5) & 7;  // dim octet

  const bf16* sbase = (sg == 0) ? kbase : vbase;

  // prologue: stage K(0), V(0)
  {
    bf16x8 s0 = *(const bf16x8*)(sbase + (size_t)(2 * kp) * D3 + oc * 8);
    bf16x8 s1 = *(const bf16x8*)(sbase + (size_t)(2 * kp + 1) * D3 + oc * 8);
    if (sg == 0) {
      *(bf16x8*)(&Kt[2 * kp][oc * 8]) = s0;
      *(bf16x8*)(&Kt[2 * kp + 1][oc * 8]) = s1;
    } else {
#pragma unroll
      for (int j = 0; j < 8; ++j) {
        bf16x2 pr;
        pr[0] = s0[j];
        pr[1] = s1[j];
        *(bf16x2*)(&Vt[oc * 8 + j][2 * kp]) = pr;
      }
    }
  }
  __syncthreads();

  for (int t = 0; t < S; t += 64) {
    const bool havenext = (t + 64 < S);

    // issue next tile's loads FIRST (each wave stages only K or V)
    bf16x8 n0r, n1r;
    if (havenext) {
      const bf16* sb = sbase + (size_t)(t + 64) * D3;
      n0r = *(const bf16x8*)(sb + (size_t)(2 * kp) * D3 + oc * 8);
      n1r = *(const bf16x8*)(sb + (size_t)(2 * kp + 1) * D3 + oc * 8);
    }

    // K·Q^T: sc[ct][r] = score(key = t + ct*16 + lhi*4 + r, qrow = l16)
    f32x4 sc[4] = {};
    __builtin_amdgcn_s_setprio(1);
#pragma unroll
    for (int ct = 0; ct < 4; ++ct) {
#pragma unroll
      for (int ks = 0; ks < 2; ++ks) {
        bf16x8 kf = *(const bf16x8*)(&Kt[ct * 16 + l16][ks * 32 + lhi * 8]);
        sc[ct] = __builtin_amdgcn_mfma_f32_16x16x32_bf16(kf, qf[ks], sc[ct], 0, 0, 0);
      }
    }
    __builtin_amdgcn_s_setprio(0);

    // barrier A: all waves' K reads retired -> K(t+1) may overwrite Kt
    __syncthreads();
    if (havenext && sg == 0) {
      *(bf16x8*)(&Kt[2 * kp][oc * 8]) = n0r;
      *(bf16x8*)(&Kt[2 * kp + 1][oc * 8]) = n1r;
    }

    // softmax (shuffle-free common path; defer-max)
    {
      float cm[4];
#pragma unroll
      for (int ct = 0; ct < 4; ++ct)
        cm[ct] = fmaxf(fmaxf(sc[ct][0], sc[ct][1]), fmaxf(sc[ct][2], sc[ct][3]));
      float mxs = fmaxf(fmaxf(cm[0], cm[1]), fmaxf(cm[2], cm[3])) * SCL;
      if (!__all(mxs - m_i <= THR)) {
        float mw = mxs;
        mw = fmaxf(mw, __shfl_xor(mw, 16));
        mw = fmaxf(mw, __shfl_xor(mw, 32));
        float nm = fmaxf(m_i, mw);
        float alpha = __builtin_amdgcn_exp2f(m_i - nm);
        m_i = nm;
        l_p *= alpha;
#pragma unroll
        for (int dt = 0; dt < 4; ++dt)
#pragma unroll
          for (int r = 0; r < 4; ++r) o[dt][r] *= alpha;
      }
      float rs4[4];
#pragma unroll
      for (int ct = 0; ct < 4; ++ct) {
#pragma unroll
        for (int r = 0; r < 4; ++r) {
          float p = __builtin_amdgcn_exp2f(__builtin_fmaf(sc[ct][r], SCL, -m_i));
          sc[ct][r] = p;
        }
        rs4[ct] = (sc[ct][0] + sc[ct][1]) + (sc[ct][2] + sc[ct][3]);
      }
      l_p += (rs4[0] + rs4[1]) + (rs4[2] + rs4[3]);
    }

    // P stage via wave-private Pq
#pragma unroll
    for (int ct = 0; ct < 4; ++ct) {
      bf16x4 pk;
#pragma unroll
      for (int r = 0; r < 4; ++r) pk[r] = (bf16)sc[ct][r];
      *(bf16x4*)(&Pq[wid][l16][ct * 16 + lhi * 4]) = pk;
    }
    bf16x8 pf0 = *(const bf16x8*)(&Pq[wid][l16][lhi * 8]);
    bf16x8 pf1 = *(const bf16x8*)(&Pq[wid][l16][32 + lhi * 8]);

    // PV: o += V^T x P
    __builtin_amdgcn_s_setprio(1);
#pragma unroll
    for (int dt = 0; dt < 4; ++dt) {
      bf16x8 vf0 = *(const bf16x8*)(&Vt[dt * 16 + l16][lhi * 8]);
      bf16x8 vf1 = *(const bf16x8*)(&Vt[dt * 16 + l16][32 + lhi * 8]);
      o[dt] = __builtin_amdgcn_mfma_f32_16x16x32_bf16(vf0, pf0, o[dt], 0, 0, 0);
      o[dt] = __builtin_amdgcn_mfma_f32_16x16x32_bf16(vf1, pf1, o[dt], 0, 0, 0);
    }
    __builtin_amdgcn_s_setprio(0);

    // barrier B: all PV reads retired (and K writes visible) -> V(t+1) write
    __syncthreads();
    if (havenext && sg == 1) {
#pragma unroll
      for (int j = 0; j < 8; ++j) {
        bf16x2 pr;
        pr[0] = n0r[j];
        pr[1] = n1r[j];
        *(bf16x2*)(&Vt[oc * 8 + j][2 * kp]) = pr;
      }
    }
  }

  // epilogue: reduce l across the 4 lanes of the q-row, normalize, store
  {
    float l_i = l_p;
    l_i += __shfl_xor(l_i, 16);
    l_i += __shfl_xor(l_i, 32);
    float rl = 1.0f / l_i;
#pragma unroll
    for (int dt = 0; dt < 4; ++dt) {
      bf16x4 ok;
#pragma unroll
      for (int r = 0; r < 4; ++r) ok[r] = (bf16)(o[dt][r] * rl);
      *(bf16x4*)(&Pq[wid][l16][dt * 16 + lhi * 4]) = ok;
    }
    bf16x8 r0 = *(const bf16x8*)(&Pq[wid][l16][lhi * 16]);
    bf16x8 r1 = *(const bf16x8*)(&Pq[wid][l16][lhi * 16 + 8]);
    bf16* orow = qbase + (size_t)(q0 + l16) * D3 + lhi * 16;
    *(bf16x8*)(orow) = r0;
    *(bf16x8*)(orow + 8) = r1;
  }
}

// ---------------------------------------------------------------------------
extern "C" void kernel_launch(void* const* d_in, const int* in_sizes, int n_in,
                              void* d_out, int out_size, void* d_ws,
                              size_t ws_size, hipStream_t stream) {
  constexpr int B = 4, S = 2048, D = 1024;

  const float* x = nullptr;
  const float* w_in = nullptr;
  const float* w_out = nullptr;
  const float* b_out = nullptr;
  for (int i = 0; i < n_in; ++i) {
    switch (in_sizes[i]) {
      case 8388608: x = (const float*)d_in[i]; break;
      case 3145728: w_in = (const float*)d_in[i]; break;
      case 1048576: w_out = (const float*)d_in[i]; break;
      case 1024: b_out = (const float*)d_in[i]; break;
    }
  }
  float* out = (float*)d_out;  // [4,2048,1024] fp32

  bf16* qkv = (bf16*)d_ws;
  const size_t need_full = (size_t)B * S * 3 * D * 2;      // 48 MiB (qkv)
  const size_t need_cvt = need_full +
                          ((size_t)B * S * D +              // x  bf16
                           (size_t)3 * D * D +              // w_in bf16
                           (size_t)D * D) * 2;              // w_out bf16

  if (ws_size >= need_cvt) {
    bf16* xb = qkv + (size_t)B * S * 3 * D;
    bf16* w_inb = xb + (size_t)B * S * D;
    bf16* w_outb = w_inb + (size_t)3 * D * D;
    const int nx8 = B * S * D / 8;
    const int nwi8 = 3 * D * D / 8;
    const int nwo8 = D * D / 8;
    cvt_bf16<<<dim3((nx8 + 255) / 256), 256, 0, stream>>>(x, xb, nx8);
    cvt_bf16<<<dim3((nwi8 + 255) / 256), 256, 0, stream>>>(w_in, w_inb, nwi8);
    cvt_bf16<<<dim3((nwo8 + 255) / 256), 256, 0, stream>>>(w_out, w_outb, nwo8);

    // G1: N=3072 = 16 x 192 -> 512 blocks
    gemm_192<bf16, false><<<dim3(3 * D / 192, B * S / 256), 512, 0, stream>>>(
        xb, w_inb, nullptr, qkv, B * S, 3 * D, D, D);
    // attn: 1024 blocks (4/CU), 8 waves x 16 q-rows
    attn_fwd<<<dim3(S / 128, B * 16), 512, 0, stream>>>(qkv);
    // G2: N=1024 -> 256x128 tile
    gemm_8ph<float, true><<<dim3(D / 128, B * S / 256), 512, 0, stream>>>(
        qkv, w_outb, b_out, out, B * S, D, D, 3 * D);
  } else if (ws_size >= need_full) {
    gemm_bt<float, bf16, false><<<dim3(3 * D / 128, B * S / 128), 256, 0,
                                  stream>>>(x, w_in, nullptr, qkv, B * S,
                                            3 * D, D, D, 0);
    attn_fwd<<<dim3(S / 128, B * 16), 512, 0, stream>>>(qkv);
    gemm_bt<bf16, float, true><<<dim3(D / 128, B * S / 128), 256, 0, stream>>>(
        qkv, w_out, b_out, out, B * S, D, D, 3 * D, 0);
  } else {
    for (int b0 = 0; b0 < B; ++b0) {
      gemm_bt<float, bf16, false><<<dim3(3 * D / 128, S / 128), 256, 0,
                                    stream>>>(x, w_in, nullptr, qkv, S, 3 * D,
                                              D, D, b0 * S);
      attn_fwd<<<dim3(S / 128, 16), 512, 0, stream>>>(qkv);
      gemm_bt<bf16, float, true><<<dim3(D / 128, S / 128), 256, 0, stream>>>(
          qkv, w_out, b_out, out + (size_t)b0 * S * D, S, D, D, 3 * D, 0);
    }
  }
}